// Round 12
// baseline (201.613 us; speedup 1.0000x reference)
//
#include <hip/hip_runtime.h>
#include <hip/hip_bf16.h>
#include <math.h>

typedef _Float16 f16x8 __attribute__((ext_vector_type(8)));
typedef _Float16 f16x4 __attribute__((ext_vector_type(4)));
typedef float f32x4 __attribute__((ext_vector_type(4)));

#define LDH 264  // 256 + 8 f16 pad -> row stride 132 dwords (4-bank rotation)

// ---------------- fused prep ----------------------------------------------------
// blocks 0..47: W2/W3/W4 -> f16 fragment-contiguous (16x16 layout), LDS-staged:
//   frag = (L*16+cg)*8+kk ; col = cg*16+(l&15) ; k = kk*32+(l>>4)*8+e
// blocks 48..207: A/B projection, f16 out, b1 folded into A
__global__ void prep(const float* __restrict__ x, const float* __restrict__ W1,
                     const float* __restrict__ b1,
                     const float* __restrict__ W2, const float* __restrict__ W3,
                     const float* __restrict__ W4,
                     _Float16* __restrict__ A, _Float16* __restrict__ B,
                     _Float16* __restrict__ Wt) {
    if (blockIdx.x < 48) {
        __shared__ _Float16 ws[256 * 17];      // [k][c], pad 17
        int L = blockIdx.x >> 4, cg = blockIdx.x & 15;
        const float* W = (L == 0) ? W2 : (L == 1) ? W3 : W4;
        int t = threadIdx.x;
        for (int i = t; i < 4096; i += 512) {
            int k = i >> 4, c = i & 15;
            ws[k * 17 + c] = (_Float16)W[k * 256 + cg * 16 + c];
        }
        __syncthreads();
        int l = t >> 3, e = t & 7;
        int c = l & 15, kb = (l >> 4) * 8 + e;
        _Float16* dst = Wt + (size_t)((L * 16 + cg) * 8) * 512 + t;
#pragma unroll
        for (int kk = 0; kk < 8; kk++)
            dst[kk * 512] = ws[(kk * 32 + kb) * 17 + c];
        return;
    }
    __shared__ float xs[258 * 4];
    int blk = blockIdx.x - 48;
    int bs = blk >> 2, pg = blk & 3;           // 4 p-values per block
    for (int i = threadIdx.x; i < 1024; i += 512) {
        int c = i >> 2, pp = i & 3;
        xs[i] = x[bs * 4096 + c * 16 + pg * 4 + pp];
    }
    if (threadIdx.x < 8) {
        int pp = threadIdx.x & 3, c = 256 + (threadIdx.x >> 2);
        int p = pg * 4 + pp;
        xs[c * 4 + pp] = (float)((c == 256) ? (p >> 2) : (p & 3)) * 0.25f;
    }
    __syncthreads();
    int half = threadIdx.x >> 8;               // 0 -> A, 1 -> B
    int col  = threadIdx.x & 255;
    float acc[4] = {0.f, 0.f, 0.f, 0.f};
    const float* Wp = W1 + half * 258 * 256 + col;
#pragma unroll 1
    for (int c0 = 0; c0 < 256; c0 += 8) {
        float w[8];
#pragma unroll
        for (int j = 0; j < 8; j++) w[j] = Wp[(c0 + j) * 256];
#pragma unroll
        for (int j = 0; j < 8; j++)
#pragma unroll
            for (int pp = 0; pp < 4; pp++) acc[pp] += xs[(c0 + j) * 4 + pp] * w[j];
    }
#pragma unroll
    for (int c = 256; c < 258; c++) {
        float w = Wp[c * 256];
#pragma unroll
        for (int pp = 0; pp < 4; pp++) acc[pp] += xs[c * 4 + pp] * w;
    }
    _Float16* out = half ? B : A;
    float bias = half ? 0.f : b1[col];         // fold b1 into A once
#pragma unroll
    for (int pp = 0; pp < 4; pp++)
        out[(bs * 16 + pg * 4 + pp) * 256 + col] = (_Float16)(acc[pp] + bias);
}

// ---------------- the big fused kernel ------------------------------------------
// grid 6400 = (b,s1,s2) x 8 row-groups of 32; 128 threads = 2 waves, each wave
// 32 rows x 128 cols as acc[2][8] of 16x16x32 MFMA (16 indep chains, 64 AGPR).
// LDS 16.9 KB -> 8 blocks/CU (16 waves, reg-capped), 2-wave barrier domain ->
// maximal phase drift across the 8 resident blocks.
__global__ __launch_bounds__(128, 4) void pairnet(
        const _Float16* __restrict__ A, const _Float16* __restrict__ B,
        const _Float16* __restrict__ Wt,
        const float* __restrict__ b2, const float* __restrict__ b3,
        const float* __restrict__ b4, float* __restrict__ pooled) {
    __shared__ _Float16 hb[32 * LDH];          // 16.9 KB

    int blk = blockIdx.x;
    int g   = blk & 7;                         // row-group: p1 in {2g, 2g+1}
    int bss = blk >> 3;                        // (b*20+s1)*20+s2, 0..799
    int s2  = bss % 20;
    int s1  = (bss / 20) % 20;
    int b   = bss / 400;
    int tid = threadIdx.x;

    // ---- layer 1: h1 = relu(A[b,s2,p2] + B[b,s1,p1]), packed f16 ----
    const _Float16* Abase = A + (b * 20 + s2) * 16 * 256;
    const _Float16* Bbase = B + ((b * 20 + s1) * 16 + g * 2) * 256;
#pragma unroll
    for (int it = 0; it < 8; it++) {
        int u = it * 128 + tid;            // 0..1023 8-col units
        int r = u >> 5;                    // row 0..31 (= (p1&1)*16 + p2)
        int c = (u & 31) * 8;              // col
        f16x8 av = *(const f16x8*)(Abase + (r & 15) * 256 + c);
        f16x8 bv = *(const f16x8*)(Bbase + (r >> 4) * 256 + c);
        f16x8 hv = av + bv;
#pragma unroll
        for (int j = 0; j < 8; j++)
            hv[j] = hv[j] > (_Float16)0.f ? hv[j] : (_Float16)0.f;
        *(f16x8*)(hb + r * LDH + c) = hv;
    }
    __syncthreads();

    int wid = tid >> 6, lane = tid & 63;
    int col0 = wid * 128;                  // wave owns 128 cols x all 32 rows
    int lr = lane & 15, lk = lane >> 4;

#pragma unroll
    for (int L = 0; L < 3; L++) {
        const float* bias = (L == 0) ? b2 : (L == 1) ? b3 : b4;
        // fragment-contiguous W base for this wave's 8 col-groups
        const _Float16* wb = Wt + (size_t)((L * 16 + wid * 8) * 8) * 512 + lane * 8;

        // bias-init accumulators (epilogue bias-add eliminated)
        f32x4 acc[2][8];
#pragma unroll
        for (int n = 0; n < 8; n++) {
            int cb = col0 + 16 * n + 4 * lk;
            float4 bv = *(const float4*)(bias + cb);
            f32x4 iv; iv[0] = bv.x; iv[1] = bv.y; iv[2] = bv.z; iv[3] = bv.w;
            acc[0][n] = iv; acc[1][n] = iv;
        }

#pragma unroll
        for (int kk = 0; kk < 8; kk++) {
            f16x8 w[8], a[2];
#pragma unroll
            for (int n = 0; n < 8; n++)
                w[n] = *(const f16x8*)(wb + (n * 8 + kk) * 512);
#pragma unroll
            for (int m = 0; m < 2; m++)
                a[m] = *(const f16x8*)(hb + (16 * m + lr) * LDH + kk * 32 + 8 * lk);
            // swapped operands -> transposed D: thread holds row 16m+lr,
            // cols col0+16n+4lk+{0..3}
#pragma unroll
            for (int m = 0; m < 2; m++)
#pragma unroll
                for (int n = 0; n < 8; n++)
                    acc[m][n] = __builtin_amdgcn_mfma_f32_16x16x32_f16(
                        w[n], a[m], acc[m][n], 0, 0, 0);
        }

        if (L < 2) {
            __syncthreads();               // all reads of hb complete
#pragma unroll
            for (int n = 0; n < 8; n++) {
                int cb = col0 + 16 * n + 4 * lk;
#pragma unroll
                for (int m = 0; m < 2; m++) {
                    int row = 16 * m + lr;
                    f16x4 hv;
                    hv[0] = (_Float16)fmaxf(acc[m][n][0], 0.f);
                    hv[1] = (_Float16)fmaxf(acc[m][n][1], 0.f);
                    hv[2] = (_Float16)fmaxf(acc[m][n][2], 0.f);
                    hv[3] = (_Float16)fmaxf(acc[m][n][3], 0.f);
                    *(f16x4*)(hb + row * LDH + cb) = hv;
                }
            }
            __syncthreads();               // writes visible
        } else {
            // layer 4: relu (bias in acc), pool 32 rows: m in-thread + lr
            // butterfly, then one atomicAdd per output element (8 g-blocks
            // of the same bss accumulate into the shared pooled row)
#pragma unroll
            for (int n = 0; n < 8; n++) {
                int cb = col0 + 16 * n + 4 * lk;
                f32x4 s;
#pragma unroll
                for (int j = 0; j < 4; j++)
                    s[j] = fmaxf(acc[0][n][j], 0.f) + fmaxf(acc[1][n][j], 0.f);
#pragma unroll
                for (int mask = 1; mask <= 8; mask <<= 1) {
#pragma unroll
                    for (int j = 0; j < 4; j++) s[j] += __shfl_xor(s[j], mask);
                }
                if (lr == 0) {
                    float* pp = pooled + (size_t)bss * 256 + cb;
#pragma unroll
                    for (int j = 0; j < 4; j++) atomicAdd(pp + j, s[j]);
                }
            }
        }
    }
}

// ---------------- final MLP on pooled [800,256] ---------------------------------
// 100 blocks x 512 threads; 8 rows/block; k-loop split across 2 thread-halves.
__global__ void final_mlp(const float* __restrict__ pooled,
        const float* __restrict__ Wf1, const float* __restrict__ bf1,
        const float* __restrict__ Wf2, const float* __restrict__ bf2,
        const float* __restrict__ Wf3, const float* __restrict__ bf3,
        const float* __restrict__ Wf4, const float* __restrict__ bf4,
        float* __restrict__ out) {
    __shared__ float p[8][256], ps[2][8][256], yb[8][256], zb[8][256], y3[8][29];
    int r0 = blockIdx.x * 8;
    int t  = threadIdx.x;
    int kh = t >> 8, col = t & 255;
    for (int i = t; i < 2048; i += 512)
        p[i >> 8][i & 255] = pooled[(size_t)r0 * 256 + i];
    __syncthreads();

    float acc[8];
#pragma unroll
    for (int r = 0; r < 8; r++) acc[r] = 0.f;
#pragma unroll 1
    for (int k0 = kh * 128; k0 < kh * 128 + 128; k0 += 8) {
        float w[8];
#pragma unroll
        for (int j = 0; j < 8; j++) w[j] = Wf1[(k0 + j) * 256 + col];
#pragma unroll
        for (int j = 0; j < 8; j++)
#pragma unroll
            for (int r = 0; r < 8; r++) acc[r] += p[r][k0 + j] * w[j];
    }
#pragma unroll
    for (int r = 0; r < 8; r++) ps[kh][r][col] = acc[r];
    __syncthreads();
    if (t < 256) {
#pragma unroll
        for (int r = 0; r < 8; r++)
            yb[r][t] = fmaxf(ps[0][r][t] + ps[1][r][t] + bf1[t], 0.f);
    }
    __syncthreads();

#pragma unroll
    for (int r = 0; r < 8; r++) acc[r] = 0.f;
#pragma unroll 1
    for (int k0 = kh * 128; k0 < kh * 128 + 128; k0 += 8) {
        float w[8];
#pragma unroll
        for (int j = 0; j < 8; j++) w[j] = Wf2[(k0 + j) * 256 + col];
#pragma unroll
        for (int j = 0; j < 8; j++)
#pragma unroll
            for (int r = 0; r < 8; r++) acc[r] += yb[r][k0 + j] * w[j];
    }
#pragma unroll
    for (int r = 0; r < 8; r++) ps[kh][r][col] = acc[r];
    __syncthreads();
    if (t < 256) {
#pragma unroll
        for (int r = 0; r < 8; r++)
            zb[r][t] = fmaxf(ps[0][r][t] + ps[1][r][t] + bf2[t], 0.f);
    }
    __syncthreads();

    if (t < 232) {
        int r = t / 29, c = t % 29;
        float a = bf3[c];
#pragma unroll 1
        for (int k0 = 0; k0 < 256; k0 += 8) {
            float w[8];
#pragma unroll
            for (int j = 0; j < 8; j++) w[j] = Wf3[(k0 + j) * 29 + c];
#pragma unroll
            for (int j = 0; j < 8; j++) a += zb[r][k0 + j] * w[j];
        }
        y3[r][c] = fmaxf(a, 0.f);
    }
    __syncthreads();
    if (t < 8) {
        float zz = bf4[0];
#pragma unroll
        for (int c = 0; c < 29; c++) zz += y3[t][c] * Wf4[c];
        out[r0 + t] = 1.f / (1.f + expf(-zz));
    }
}

extern "C" void kernel_launch(void* const* d_in, const int* in_sizes, int n_in,
                              void* d_out, int out_size, void* d_ws, size_t ws_size,
                              hipStream_t stream) {
    const float* x   = (const float*)d_in[0];
    const float* W1  = (const float*)d_in[1];
    const float* b1  = (const float*)d_in[2];
    const float* W2  = (const float*)d_in[3];
    const float* b2  = (const float*)d_in[4];
    const float* W3  = (const float*)d_in[5];
    const float* b3  = (const float*)d_in[6];
    const float* W4  = (const float*)d_in[7];
    const float* b4  = (const float*)d_in[8];
    const float* Wf1 = (const float*)d_in[9];
    const float* bf1 = (const float*)d_in[10];
    const float* Wf2 = (const float*)d_in[11];
    const float* bf2 = (const float*)d_in[12];
    const float* Wf3 = (const float*)d_in[13];
    const float* bf3 = (const float*)d_in[14];
    const float* Wf4 = (const float*)d_in[15];
    const float* bf4 = (const float*)d_in[16];

    float* pooled = (float*)d_ws;                      // 800*256 f32
    _Float16* A   = (_Float16*)(pooled + 800 * 256);   // 640*256 f16
    _Float16* Bp  = A + 640 * 256;                     // 640*256 f16
    _Float16* Wt  = Bp + 640 * 256;                    // 384 frags * 512 f16

    hipMemsetAsync(pooled, 0, 800 * 256 * sizeof(float), stream);
    prep<<<208, 512, 0, stream>>>(x, W1, b1, W2, W3, W4, A, Bp, Wt);
    pairnet<<<6400, 128, 0, stream>>>(A, Bp, Wt, b2, b3, b4, pooled);
    final_mlp<<<100, 512, 0, stream>>>(pooled, Wf1, bf1, Wf2, bf2, Wf3, bf3,
                                       Wf4, bf4, (float*)d_out);
}